// Round 3
// baseline (218.945 us; speedup 1.0000x reference)
//
#include <hip/hip_runtime.h>
#include <stdint.h>

#define EPSV 1e-5f

typedef __attribute__((ext_vector_type(4))) float f32x4;
typedef __attribute__((ext_vector_type(8))) short bf16x8;

__device__ __forceinline__ unsigned short f2bf(float x){
  union{float f; uint32_t u;} a; a.f=x;
  uint32_t r = a.u + 0x7fffu + ((a.u>>16)&1u);
  return (unsigned short)(r>>16);
}
__device__ __forceinline__ float bf2f(unsigned short u){
  union{uint32_t x; float f;} a; a.x = (uint32_t)u<<16; return a.f;
}
// split float into bf16 hi (truncated) + bf16 lo (RNE of remainder)
__device__ __forceinline__ void split2(float x, unsigned short& h, unsigned short& l){
  union{float f; uint32_t u;} a; a.f=x;
  union{uint32_t u; float f;} b; b.u = a.u & 0xffff0000u;
  h = (unsigned short)(b.u>>16);
  l = f2bf(x - b.f);
}
__device__ __forceinline__ f32x4 mfma16(bf16x8 a, bf16x8 b, f32x4 c){
  return __builtin_amdgcn_mfma_f32_16x16x32_bf16(a, b, c, 0, 0, 0);
}
__device__ __forceinline__ f32x4 vmax4(f32x4 a, f32x4 b){
  f32x4 r; r[0]=fmaxf(a[0],b[0]); r[1]=fmaxf(a[1],b[1]);
  r[2]=fmaxf(a[2],b[2]); r[3]=fmaxf(a[3],b[3]); return r;
}

#define QF 0.25503464f   /* 1/sqrt(32) * log2(e) */

// ---------------- GEMM + BN ----------------
// mode 0: Out[b][o][n] = BN(W X) fp32 (proj)
// mode 1: qkv — q/k channels -> qk32 [b*8+h][64][4096] f32 (q pre-scaled by QF);
//               v channels  -> vh/vl bf16 planes [b*8+h][32][4096]
__global__ __launch_bounds__(256)
void gemm_bn_kernel(const float* __restrict__ W, const float* __restrict__ X,
                    float* __restrict__ Out,
                    float* __restrict__ qk32,
                    unsigned short* __restrict__ vhp, unsigned short* __restrict__ vlp,
                    const float* __restrict__ gg, const float* __restrict__ bb,
                    const float* __restrict__ bm, const float* __restrict__ bv,
                    int M, int mode)
{
  const int t = threadIdx.x;
  const int lane = t & 63, wid = t >> 6;
  const int nblk = blockIdx.x;
  const int mblk = blockIdx.y;
  const int b    = blockIdx.z;
  const int N = 4096, K = 256;

  __shared__ __align__(16) unsigned short Ah[128][40], Al[128][40];
  __shared__ __align__(16) unsigned short Bh[128][40], Bl[128][40];
  __shared__ float scale_s[128], shift_s[128];

  if (t < 128){
    int o = mblk*128 + t;
    float s = gg[o]*rsqrtf(bv[o] + EPSV);
    float sh = bb[o] - bm[o]*s;
    if (mode == 1 && (o % 96) < 32){ s *= QF; sh *= QF; }
    scale_s[t] = s;
    shift_s[t] = sh;
  }
  __syncthreads();

  const float* Xb = X + (size_t)b*K*N;

  f32x4 acc[4][4];
  #pragma unroll
  for (int i=0;i<4;i++)
    #pragma unroll
    for (int j=0;j<4;j++){ f32x4 z = {0.f,0.f,0.f,0.f}; acc[i][j] = z; }

  const int wr = (wid>>1)*64, wc = (wid&1)*64;

  for (int ks = 0; ks < 8; ++ks){
    #pragma unroll
    for (int i=0;i<4;i++){
      int idx = t + i*256;
      int row = idx >> 3;
      int c4  = idx & 7;
      const float* wp = W + (size_t)(mblk*128+row)*K + ks*32 + c4*4;
      f32x4 v = *(const f32x4*)wp;
      float s = scale_s[row];
      #pragma unroll
      for (int j=0;j<4;j++){
        unsigned short hh, ll; split2(v[j]*s, hh, ll);
        Ah[row][c4*4+j]=hh; Al[row][c4*4+j]=ll;
      }
    }
    #pragma unroll
    for (int i=0;i<4;i++){
      int idx = t + i*256;
      int crow = idx >> 5;
      int n4 = idx & 31;
      const float* xp = Xb + (size_t)(ks*32 + crow)*N + nblk*128 + n4*4;
      f32x4 v = *(const f32x4*)xp;
      #pragma unroll
      for (int j=0;j<4;j++){
        unsigned short hh, ll; split2(v[j], hh, ll);
        Bh[n4*4+j][crow]=hh; Bl[n4*4+j][crow]=ll;
      }
    }
    __syncthreads();

    bf16x8 ah[4], al[4], bh[4], bl[4];
    #pragma unroll
    for (int i=0;i<4;i++){
      ah[i] = *(const bf16x8*)&Ah[wr + i*16 + (lane&15)][(lane>>4)*8];
      al[i] = *(const bf16x8*)&Al[wr + i*16 + (lane&15)][(lane>>4)*8];
      bh[i] = *(const bf16x8*)&Bh[wc + i*16 + (lane&15)][(lane>>4)*8];
      bl[i] = *(const bf16x8*)&Bl[wc + i*16 + (lane&15)][(lane>>4)*8];
    }
    #pragma unroll
    for (int i=0;i<4;i++)
      #pragma unroll
      for (int j=0;j<4;j++){
        acc[i][j] = mfma16(ah[i], bh[j], acc[i][j]);
        acc[i][j] = mfma16(al[i], bh[j], acc[i][j]);
        acc[i][j] = mfma16(ah[i], bl[j], acc[i][j]);
      }
    __syncthreads();
  }

  if (mode == 0){
    #pragma unroll
    for (int i=0;i<4;i++)
      #pragma unroll
      for (int j=0;j<4;j++){
        int lrow0 = wr + i*16 + ((lane>>4)<<2);
        int ocol  = nblk*128 + wc + j*16 + (lane&15);
        float* op = Out + ((size_t)b*M + (size_t)(mblk*128 + lrow0))*N + ocol;
        #pragma unroll
        for (int r=0;r<4;r++)
          op[(size_t)r*N] = acc[i][j][r] + shift_s[lrow0 + r];
      }
  } else {
    #pragma unroll
    for (int i=0;i<4;i++){
      int base = mblk*128 + wr + i*16;   // multiple of 16; type uniform per i
      int hh = base/96;
      int rem = base - hh*96;
      #pragma unroll
      for (int j=0;j<4;j++){
        int ocol = nblk*128 + wc + j*16 + (lane&15);
        #pragma unroll
        for (int r=0;r<4;r++){
          int off = ((lane>>4)<<2) + r;
          float val = acc[i][j][r] + shift_s[wr + i*16 + off];
          if (rem < 64){
            qk32[((size_t)(b*8+hh)*64 + rem + off)*4096 + ocol] = val;
          } else {
            unsigned short h2, l2; split2(val, h2, l2);
            size_t vidx = ((size_t)(b*8+hh)*32 + (rem-64) + off)*4096 + ocol;
            vhp[vidx] = h2; vlp[vidx] = l2;
          }
        }
      }
    }
  }
}

// ---------------- repack q/k: [bh][64][4096] f32 -> 4 u16 planes [(ba*8+h)][1024][32] ----------------
__global__ __launch_bounds__(256)
void repack_qk(const float* __restrict__ qk32,
               uint16_t* __restrict__ qth, uint16_t* __restrict__ qtl,
               uint16_t* __restrict__ kth, uint16_t* __restrict__ ktl)
{
  const int t = threadIdx.x;
  const int nch  = blockIdx.x;   // 0..31: 128-n chunk
  const int type = blockIdx.y;   // 0 q, 1 k
  const int bh   = blockIdx.z;   // 0..15
  __shared__ __align__(16) float tile[32][132];
  const float* src = qk32 + ((size_t)bh*64 + type*32)*4096 + nch*128;
  {
    int d = t>>3, m16 = (t&7)*16;
    const float* sp = src + (size_t)d*4096 + m16;
    *(f32x4*)&tile[d][m16]    = *(const f32x4*)(sp);
    *(f32x4*)&tile[d][m16+4]  = *(const f32x4*)(sp+4);
    *(f32x4*)&tile[d][m16+8]  = *(const f32x4*)(sp+8);
    *(f32x4*)&tile[d][m16+12] = *(const f32x4*)(sp+12);
  }
  __syncthreads();
  {
    int m = t>>1, dh = (t&1)*16;
    int b = bh>>3, h = bh&7;
    int n = nch*128 + m;
    int area = n>>10, mm = n&1023;
    size_t off = ((size_t)((b*4+area)*8 + h)*1024 + mm)*32 + dh;
    uint16_t* dh_ = (type ? kth : qth) + off;
    uint16_t* dl_ = (type ? ktl : qtl) + off;
    uint16_t hi[16], lo[16];
    #pragma unroll
    for (int kk=0; kk<16; kk++)
      split2(tile[dh+kk][m], hi[kk], lo[kk]);
    *(uint4*)(dh_)     = *(const uint4*)&hi[0];
    *(uint4*)(dh_ + 8) = *(const uint4*)&hi[8];
    *(uint4*)(dl_)     = *(const uint4*)&lo[0];
    *(uint4*)(dl_ + 8) = *(const uint4*)&lo[8];
  }
}

// ---------------- LDS-free flash attention (16 q-rows per wave, XCD-packed) ----------------
// planes: [(ba*8+h)][m 1024][d 32] u16; vh: [b*8+h][d 32][n 4096] bf16
__global__ __launch_bounds__(256)
void attn_kernel(const uint16_t* __restrict__ qth, const uint16_t* __restrict__ qtl,
                 const uint16_t* __restrict__ kth, const uint16_t* __restrict__ ktl,
                 const uint16_t* __restrict__ vh, float* __restrict__ obuf)
{
  const int t = threadIdx.x, lane = t & 63, wid = t >> 6;
  const int g = lane >> 4, li = lane & 15;
  // XCD-aware decomposition: bid%8 = XCD; each XCD owns 8 whole (ba,h) problems
  const int bid  = blockIdx.x;           // 0..2047
  const int xcd  = bid & 7;
  const int kk   = bid >> 3;             // 0..255
  const int prob = xcd*8 + (kk>>4);      // 0..63  = ba*8 + h
  const int nblk = kk & 15;              // 0..15
  const int ba = prob >> 3, h = prob & 7;
  const int b = ba >> 2, area = ba & 3;

  __shared__ __align__(16) unsigned short pt[4][16][72];   // per-wave P^T [n][m]

  const size_t qkrow = (size_t)prob*1024;
  const int nw = nblk*64 + wid*16;       // first of this wave's 16 q rows

  // Q fragments (once): B-operand, lane holds q[n=li][d=g*8+reg]
  bf16x8 qh = *(const bf16x8*)(qth + (qkrow + nw + li)*32 + g*8);
  bf16x8 ql = *(const bf16x8*)(qtl + (qkrow + nw + li)*32 + g*8);

  const uint16_t* kbh = kth + qkrow*32;
  const uint16_t* kbl = ktl + qkrow*32;
  const uint16_t* vb  = vh + ((size_t)(b*8+h)*32)*4096 + area*1024;

  float mrun = -1e30f;
  float srun = 0.f;
  f32x4 oacc[2];
  #pragma unroll
  for (int dt=0;dt<2;dt++){ f32x4 z = {0.f,0.f,0.f,0.f}; oacc[dt] = z; }

  // K fragments for iter 0 (A-operand: lane holds K[m=li(+16mt)][d=g*8+reg])
  bf16x8 kh[4], kl[4];
  #pragma unroll
  for (int mt=0;mt<4;mt++){
    kh[mt] = *(const bf16x8*)(kbh + (size_t)(mt*16 + li)*32 + g*8);
    kl[mt] = *(const bf16x8*)(kbl + (size_t)(mt*16 + li)*32 + g*8);
  }

  for (int m0 = 0; m0 < 1024; m0 += 64){
    // V fragments (bf16-hi plane, direct from L2)
    bf16x8 vf[2][2];
    #pragma unroll
    for (int dt=0;dt<2;dt++)
      #pragma unroll
      for (int ks=0;ks<2;ks++)
        vf[dt][ks] = *(const bf16x8*)(vb + (size_t)(dt*16+li)*4096 + m0 + ks*32 + g*8);

    // S^T = K Q^T (3-term split, log2 domain)
    f32x4 s[4];
    #pragma unroll
    for (int mt=0;mt<4;mt++){
      f32x4 z = {0.f,0.f,0.f,0.f};
      z = mfma16(kh[mt], qh, z);
      z = mfma16(kl[mt], qh, z);
      z = mfma16(kh[mt], ql, z);
      s[mt] = z;
    }

    // prefetch next K
    if (m0 < 960){
      const uint16_t* nbh = kbh + (size_t)(m0+64)*32;
      const uint16_t* nbl = kbl + (size_t)(m0+64)*32;
      #pragma unroll
      for (int mt=0;mt<4;mt++){
        kh[mt] = *(const bf16x8*)(nbh + (size_t)(mt*16 + li)*32 + g*8);
        kl[mt] = *(const bf16x8*)(nbl + (size_t)(mt*16 + li)*32 + g*8);
      }
    }

    // online softmax over this lane's 16 m-values (row n = li)
    f32x4 m01 = vmax4(s[0], s[1]);
    f32x4 m23 = vmax4(s[2], s[3]);
    f32x4 mm4 = vmax4(m01, m23);
    float mx = fmaxf(fmaxf(mm4[0], mm4[1]), fmaxf(mm4[2], mm4[3]));
    mx = fmaxf(mx, __shfl_xor(mx, 16, 64));
    mx = fmaxf(mx, __shfl_xor(mx, 32, 64));
    // defer-max: only rescale when some row's max grew by >8 (log2 domain)
    if (__any(mx > mrun + 8.0f)){
      float mnew = fmaxf(mrun, mx);
      float corr = __builtin_exp2f(mrun - mnew);
      mrun = mnew;
      srun *= corr;
      #pragma unroll
      for (int dt=0;dt<2;dt++)
        #pragma unroll
        for (int r=0;r<4;r++) oacc[dt][r] *= corr;
    }
    f32x4 sum4 = {0.f,0.f,0.f,0.f};
    #pragma unroll
    for (int mt=0; mt<4; mt++){
      f32x4 p;
      #pragma unroll
      for (int r=0;r<4;r++) p[r] = __builtin_exp2f(s[mt][r] - mrun);
      sum4 += p;
      uint32_t pk01, pk23;
      asm("v_cvt_pk_bf16_f32 %0, %1, %2" : "=v"(pk01) : "v"(p[0]), "v"(p[1]));
      asm("v_cvt_pk_bf16_f32 %0, %1, %2" : "=v"(pk23) : "v"(p[2]), "v"(p[3]));
      uint2 u; u.x = pk01; u.y = pk23;
      *(uint2*)&pt[wid][li][mt*16 + g*4] = u;
    }
    float sm = sum4[0]+sum4[1]+sum4[2]+sum4[3];
    sm += __shfl_xor(sm, 16, 64);
    sm += __shfl_xor(sm, 32, 64);
    srun += sm;

    // O^T += V * P^T  (per-wave private LDS roundtrip, no barrier)
    #pragma unroll
    for (int ks=0; ks<2; ks++){
      bf16x8 pf = *(const bf16x8*)&pt[wid][li][ks*32 + g*8];
      #pragma unroll
      for (int dt=0; dt<2; dt++)
        oacc[dt] = mfma16(vf[dt][ks], pf, oacc[dt]);
    }
  }

  // epilogue
  float inv = 1.0f / srun;
  #pragma unroll
  for (int dt=0;dt<2;dt++){
    size_t base = ((size_t)b*256 + h*32 + dt*16 + g*4)*4096 + (size_t)(area*1024 + nw + li);
    #pragma unroll
    for (int r=0;r<4;r++)
      obuf[base + (size_t)r*4096] = oacc[dt][r]*inv;
  }
}

// ---------------- depthwise 7x7 conv + BN, accumulate into obuf ----------------
__global__ __launch_bounds__(256)
void dwconv_bn_add(const uint16_t* __restrict__ vhp, const uint16_t* __restrict__ vlp,
                   const float* __restrict__ wpe,
                   const float* __restrict__ gg, const float* __restrict__ bb,
                   const float* __restrict__ bm, const float* __restrict__ bv,
                   float* __restrict__ obuf)
{
  const int t = threadIdx.x;
  const int c = blockIdx.x;
  const int b = blockIdx.y;
  const size_t srow = ((size_t)(b*8 + (c>>5))*32 + (c&31))*4096;
  const uint16_t* sh_ = vhp + srow;
  const uint16_t* sl_ = vlp + srow;
  __shared__ float tile[70*70];
  for (int idx = t; idx < 4900; idx += 256){
    int y = idx/70 - 3, x = idx%70 - 3;
    float v = 0.f;
    if ((unsigned)y < 64u && (unsigned)x < 64u){
      int o = y*64 + x;
      v = bf2f(sh_[o]) + bf2f(sl_[o]);
    }
    tile[idx] = v;
  }
  float wreg[49];
  #pragma unroll
  for (int i=0;i<49;i++) wreg[i] = wpe[c*49 + i];
  float sc = gg[c]*rsqrtf(bv[c]+EPSV);
  float sb = bb[c] - bm[c]*sc;
  __syncthreads();
  float* dst = obuf + ((size_t)b*256 + c)*4096;
  #pragma unroll
  for (int p=0;p<16;p++){
    int pix = t + p*256;
    int y = pix >> 6, x = pix & 63;
    float acc = 0.f;
    #pragma unroll
    for (int ky=0;ky<7;ky++)
      #pragma unroll
      for (int kx=0;kx<7;kx++)
        acc += tile[(y+ky)*70 + x + kx] * wreg[ky*7+kx];
    dst[pix] += acc*sc + sb;
  }
}

extern "C" void kernel_launch(void* const* d_in, const int* in_sizes, int n_in,
                              void* d_out, int out_size, void* d_ws, size_t ws_size,
                              hipStream_t stream) {
  const float* x       = (const float*)d_in[0];
  const float* w_qkv   = (const float*)d_in[1];
  const float* g_qkv   = (const float*)d_in[2];
  const float* b_qkv   = (const float*)d_in[3];
  const float* m_qkv   = (const float*)d_in[4];
  const float* var_qkv = (const float*)d_in[5];
  const float* w_pe    = (const float*)d_in[6];
  const float* g_pe    = (const float*)d_in[7];
  const float* b_pe    = (const float*)d_in[8];
  const float* m_pe    = (const float*)d_in[9];
  const float* var_pe  = (const float*)d_in[10];
  const float* w_proj  = (const float*)d_in[11];
  const float* g_proj  = (const float*)d_in[12];
  const float* b_proj  = (const float*)d_in[13];
  const float* m_proj  = (const float*)d_in[14];
  const float* var_proj= (const float*)d_in[15];

  char* wsb = (char*)d_ws;
  float*     qk32 = (float*)wsb;                          // 16 MiB  [bh][64][4096]
  uint16_t*  vhp  = (uint16_t*)(wsb + 16777216);          // 4 MiB
  uint16_t*  vlp  = (uint16_t*)(wsb + 20971520);          // 4 MiB
  uint16_t*  qth  = (uint16_t*)(wsb + 25165824);          // 4 MiB
  uint16_t*  qtl  = (uint16_t*)(wsb + 29360128);          // 4 MiB
  uint16_t*  kth  = (uint16_t*)(wsb + 33554432);          // 4 MiB
  uint16_t*  ktl  = (uint16_t*)(wsb + 37748736);          // 4 MiB (total 40 MiB)
  float*     obuf = (float*)wsb;                          // aliases qk32 (dead after repack)
  float*     out  = (float*)d_out;

  gemm_bn_kernel<<<dim3(32,6,2), 256, 0, stream>>>(w_qkv, x, nullptr, qk32, vhp, vlp,
      g_qkv, b_qkv, m_qkv, var_qkv, 768, 1);
  repack_qk<<<dim3(32,2,16), 256, 0, stream>>>(qk32, qth, qtl, kth, ktl);
  attn_kernel<<<dim3(2048), 256, 0, stream>>>(qth, qtl, kth, ktl, vhp, obuf);
  dwconv_bn_add<<<dim3(256,2), 256, 0, stream>>>(vhp, vlp, w_pe,
      g_pe, b_pe, m_pe, var_pe, obuf);
  gemm_bn_kernel<<<dim3(32,2,2), 256, 0, stream>>>(w_proj, obuf, out, nullptr, nullptr, nullptr,
      g_proj, b_proj, m_proj, var_proj, 256, 0);
}

// Round 4
// 145.830 us; speedup vs baseline: 1.5014x; 1.5014x over previous
//
#include <hip/hip_runtime.h>
#include <stdint.h>

#define EPSV 1e-5f

typedef __attribute__((ext_vector_type(4))) float f32x4;
typedef __attribute__((ext_vector_type(8))) short bf16x8;

__device__ __forceinline__ unsigned short f2bf(float x){
  union{float f; uint32_t u;} a; a.f=x;
  uint32_t r = a.u + 0x7fffu + ((a.u>>16)&1u);
  return (unsigned short)(r>>16);
}
__device__ __forceinline__ float bf2f(unsigned short u){
  union{uint32_t x; float f;} a; a.x = (uint32_t)u<<16; return a.f;
}
// split float into bf16 hi (truncated) + bf16 lo (RNE of remainder)
__device__ __forceinline__ void split2(float x, unsigned short& h, unsigned short& l){
  union{float f; uint32_t u;} a; a.f=x;
  union{uint32_t u; float f;} b; b.u = a.u & 0xffff0000u;
  h = (unsigned short)(b.u>>16);
  l = f2bf(x - b.f);
}
__device__ __forceinline__ f32x4 mfma16(bf16x8 a, bf16x8 b, f32x4 c){
  return __builtin_amdgcn_mfma_f32_16x16x32_bf16(a, b, c, 0, 0, 0);
}
__device__ __forceinline__ f32x4 vmax4(f32x4 a, f32x4 b){
  f32x4 r; r[0]=fmaxf(a[0],b[0]); r[1]=fmaxf(a[1],b[1]);
  r[2]=fmaxf(a[2],b[2]); r[3]=fmaxf(a[3],b[3]); return r;
}

#define QF 0.25503464f   /* 1/sqrt(32) * log2(e) */

// ---------------- GEMM + BN ----------------
// mode 0: Out[b][o][n] = BN(W X) fp32 (proj)
// mode 1: qkv — q/k channels -> qk32 [b*8+h][64][4096] f32 (q pre-scaled by QF);
//               v channels  -> vh/vl bf16 planes [b*8+h][32][4096]
__global__ __launch_bounds__(256)
void gemm_bn_kernel(const float* __restrict__ W, const float* __restrict__ X,
                    float* __restrict__ Out,
                    float* __restrict__ qk32,
                    unsigned short* __restrict__ vhp, unsigned short* __restrict__ vlp,
                    const float* __restrict__ gg, const float* __restrict__ bb,
                    const float* __restrict__ bm, const float* __restrict__ bv,
                    int M, int mode)
{
  const int t = threadIdx.x;
  const int lane = t & 63, wid = t >> 6;
  const int nblk = blockIdx.x;
  const int mblk = blockIdx.y;
  const int b    = blockIdx.z;
  const int N = 4096, K = 256;

  __shared__ __align__(16) unsigned short Ah[128][40], Al[128][40];
  __shared__ __align__(16) unsigned short Bh[128][40], Bl[128][40];
  __shared__ float scale_s[128], shift_s[128];

  if (t < 128){
    int o = mblk*128 + t;
    float s = gg[o]*rsqrtf(bv[o] + EPSV);
    float sh = bb[o] - bm[o]*s;
    if (mode == 1 && (o % 96) < 32){ s *= QF; sh *= QF; }
    scale_s[t] = s;
    shift_s[t] = sh;
  }
  __syncthreads();

  const float* Xb = X + (size_t)b*K*N;

  f32x4 acc[4][4];
  #pragma unroll
  for (int i=0;i<4;i++)
    #pragma unroll
    for (int j=0;j<4;j++){ f32x4 z = {0.f,0.f,0.f,0.f}; acc[i][j] = z; }

  const int wr = (wid>>1)*64, wc = (wid&1)*64;

  for (int ks = 0; ks < 8; ++ks){
    #pragma unroll
    for (int i=0;i<4;i++){
      int idx = t + i*256;
      int row = idx >> 3;
      int c4  = idx & 7;
      const float* wp = W + (size_t)(mblk*128+row)*K + ks*32 + c4*4;
      f32x4 v = *(const f32x4*)wp;
      float s = scale_s[row];
      #pragma unroll
      for (int j=0;j<4;j++){
        unsigned short hh, ll; split2(v[j]*s, hh, ll);
        Ah[row][c4*4+j]=hh; Al[row][c4*4+j]=ll;
      }
    }
    #pragma unroll
    for (int i=0;i<4;i++){
      int idx = t + i*256;
      int crow = idx >> 5;
      int n4 = idx & 31;
      const float* xp = Xb + (size_t)(ks*32 + crow)*N + nblk*128 + n4*4;
      f32x4 v = *(const f32x4*)xp;
      #pragma unroll
      for (int j=0;j<4;j++){
        unsigned short hh, ll; split2(v[j], hh, ll);
        Bh[n4*4+j][crow]=hh; Bl[n4*4+j][crow]=ll;
      }
    }
    __syncthreads();

    bf16x8 ah[4], al[4], bh[4], bl[4];
    #pragma unroll
    for (int i=0;i<4;i++){
      ah[i] = *(const bf16x8*)&Ah[wr + i*16 + (lane&15)][(lane>>4)*8];
      al[i] = *(const bf16x8*)&Al[wr + i*16 + (lane&15)][(lane>>4)*8];
      bh[i] = *(const bf16x8*)&Bh[wc + i*16 + (lane&15)][(lane>>4)*8];
      bl[i] = *(const bf16x8*)&Bl[wc + i*16 + (lane&15)][(lane>>4)*8];
    }
    #pragma unroll
    for (int i=0;i<4;i++)
      #pragma unroll
      for (int j=0;j<4;j++){
        acc[i][j] = mfma16(ah[i], bh[j], acc[i][j]);
        acc[i][j] = mfma16(al[i], bh[j], acc[i][j]);
        acc[i][j] = mfma16(ah[i], bl[j], acc[i][j]);
      }
    __syncthreads();
  }

  if (mode == 0){
    #pragma unroll
    for (int i=0;i<4;i++)
      #pragma unroll
      for (int j=0;j<4;j++){
        int lrow0 = wr + i*16 + ((lane>>4)<<2);
        int ocol  = nblk*128 + wc + j*16 + (lane&15);
        float* op = Out + ((size_t)b*M + (size_t)(mblk*128 + lrow0))*N + ocol;
        #pragma unroll
        for (int r=0;r<4;r++)
          op[(size_t)r*N] = acc[i][j][r] + shift_s[lrow0 + r];
      }
  } else {
    #pragma unroll
    for (int i=0;i<4;i++){
      int base = mblk*128 + wr + i*16;   // multiple of 16; type uniform per i
      int hh = base/96;
      int rem = base - hh*96;
      #pragma unroll
      for (int j=0;j<4;j++){
        int ocol = nblk*128 + wc + j*16 + (lane&15);
        #pragma unroll
        for (int r=0;r<4;r++){
          int off = ((lane>>4)<<2) + r;
          float val = acc[i][j][r] + shift_s[wr + i*16 + off];
          if (rem < 64){
            qk32[((size_t)(b*8+hh)*64 + rem + off)*4096 + ocol] = val;
          } else {
            unsigned short h2, l2; split2(val, h2, l2);
            size_t vidx = ((size_t)(b*8+hh)*32 + (rem-64) + off)*4096 + ocol;
            vhp[vidx] = h2; vlp[vidx] = l2;
          }
        }
      }
    }
  }
}

// ---------------- repack q/k: [bh][64][4096] f32 -> 4 u16 planes [(ba*8+h)][1024][32] ----------------
__global__ __launch_bounds__(256)
void repack_qk(const float* __restrict__ qk32,
               uint16_t* __restrict__ qth, uint16_t* __restrict__ qtl,
               uint16_t* __restrict__ kth, uint16_t* __restrict__ ktl)
{
  const int t = threadIdx.x;
  const int nch  = blockIdx.x;   // 0..31: 128-n chunk
  const int type = blockIdx.y;   // 0 q, 1 k
  const int bh   = blockIdx.z;   // 0..15
  __shared__ __align__(16) float tile[32][132];
  const float* src = qk32 + ((size_t)bh*64 + type*32)*4096 + nch*128;
  {
    int d = t>>3, m16 = (t&7)*16;
    const float* sp = src + (size_t)d*4096 + m16;
    *(f32x4*)&tile[d][m16]    = *(const f32x4*)(sp);
    *(f32x4*)&tile[d][m16+4]  = *(const f32x4*)(sp+4);
    *(f32x4*)&tile[d][m16+8]  = *(const f32x4*)(sp+8);
    *(f32x4*)&tile[d][m16+12] = *(const f32x4*)(sp+12);
  }
  __syncthreads();
  {
    int m = t>>1, dh = (t&1)*16;
    int b = bh>>3, h = bh&7;
    int n = nch*128 + m;
    int area = n>>10, mm = n&1023;
    size_t off = ((size_t)((b*4+area)*8 + h)*1024 + mm)*32 + dh;
    uint16_t* dh_ = (type ? kth : qth) + off;
    uint16_t* dl_ = (type ? ktl : qtl) + off;
    uint16_t hi[16], lo[16];
    #pragma unroll
    for (int kk=0; kk<16; kk++)
      split2(tile[dh+kk][m], hi[kk], lo[kk]);
    *(uint4*)(dh_)     = *(const uint4*)&hi[0];
    *(uint4*)(dh_ + 8) = *(const uint4*)&hi[8];
    *(uint4*)(dl_)     = *(const uint4*)&lo[0];
    *(uint4*)(dl_ + 8) = *(const uint4*)&lo[8];
  }
}

// ---------------- split-m flash attention: 32 q-rows/wave, half the keys per block ----------------
// planes: [(ba*8+h)][m 1024][d 32] u16; vh: [b*8+h][d 32][n 4096] bf16
// writes partials: po bf16 [prob*2+mh][d 32][n 1024] (unnormalized), pm/ps f32 [prob*2+mh][n 1024]
__global__ __launch_bounds__(256)
void attn_kernel(const uint16_t* __restrict__ qth, const uint16_t* __restrict__ qtl,
                 const uint16_t* __restrict__ kth, const uint16_t* __restrict__ ktl,
                 const uint16_t* __restrict__ vh,
                 uint16_t* __restrict__ po, float* __restrict__ pm, float* __restrict__ ps)
{
  const int t = threadIdx.x, lane = t & 63, wid = t >> 6;
  const int g = lane >> 4, li = lane & 15;
  // XCD packing: bid&7 = XCD; each XCD owns 8 whole problems; 16 blocks/problem (8 nblk x 2 mh)
  const int bid  = blockIdx.x;           // 0..1023
  const int xcd  = bid & 7;
  const int rr   = bid >> 3;             // 0..127
  const int prob = xcd*8 + (rr >> 4);    // 0..63 (rr>>4 in 0..7) — bijective
  const int sub  = rr & 15;
  const int nblk = sub >> 1;             // 0..7
  const int mh   = sub & 1;              // 0..1 key half
  const int ba = prob >> 3, h = prob & 7;
  const int b = ba >> 2, area = ba & 3;

  __shared__ __align__(16) unsigned short pt[4][32][72];   // per-wave P^T [n][m]

  const size_t qkrow = (size_t)prob*1024;
  const int nw = nblk*128 + wid*32;      // first of this wave's 32 q rows
  const int mbase = mh*512;

  // Q fragments (B-operand): lane holds q[n=nt*16+li][d=g*8..]
  bf16x8 qh[2], ql[2];
  #pragma unroll
  for (int nt=0; nt<2; nt++){
    qh[nt] = *(const bf16x8*)(qth + (qkrow + nw + nt*16 + li)*32 + g*8);
    ql[nt] = *(const bf16x8*)(qtl + (qkrow + nw + nt*16 + li)*32 + g*8);
  }

  const uint16_t* kbh = kth + (qkrow + mbase)*32;
  const uint16_t* kbl = ktl + (qkrow + mbase)*32;
  const uint16_t* vb  = vh + ((size_t)(b*8+h)*32)*4096 + area*1024 + mbase;

  float mrun[2] = {-1e30f, -1e30f};
  float srun[2] = {0.f, 0.f};
  f32x4 oacc[2][2];
  #pragma unroll
  for (int dt=0;dt<2;dt++)
    #pragma unroll
    for (int nt=0;nt<2;nt++){ f32x4 z = {0.f,0.f,0.f,0.f}; oacc[dt][nt] = z; }

  // K fragments for iter 0 (A-operand): lane holds K[m=mt*16+li][d=g*8..]
  bf16x8 kh[4], kl[4];
  #pragma unroll
  for (int mt=0;mt<4;mt++){
    kh[mt] = *(const bf16x8*)(kbh + (size_t)(mt*16 + li)*32 + g*8);
    kl[mt] = *(const bf16x8*)(kbl + (size_t)(mt*16 + li)*32 + g*8);
  }

  for (int m0 = 0; m0 < 512; m0 += 64){
    // V fragments (bf16-hi plane, direct from L2)
    bf16x8 vf[2][2];
    #pragma unroll
    for (int dt=0;dt<2;dt++)
      #pragma unroll
      for (int ks=0;ks<2;ks++)
        vf[dt][ks] = *(const bf16x8*)(vb + (size_t)(dt*16+li)*4096 + m0 + ks*32 + g*8);

    // S^T = K Q^T (3-term split, log2 domain); lane gets m=mt*16+g*4+r, n=nt*16+li
    f32x4 s[4][2];
    #pragma unroll
    for (int mt=0;mt<4;mt++)
      #pragma unroll
      for (int nt=0;nt<2;nt++){
        f32x4 z = {0.f,0.f,0.f,0.f};
        z = mfma16(kh[mt], qh[nt], z);
        z = mfma16(kl[mt], qh[nt], z);
        z = mfma16(kh[mt], ql[nt], z);
        s[mt][nt] = z;
      }

    // prefetch next K
    if (m0 < 448){
      const uint16_t* nbh = kbh + (size_t)(m0+64)*32;
      const uint16_t* nbl = kbl + (size_t)(m0+64)*32;
      #pragma unroll
      for (int mt=0;mt<4;mt++){
        kh[mt] = *(const bf16x8*)(nbh + (size_t)(mt*16 + li)*32 + g*8);
        kl[mt] = *(const bf16x8*)(nbl + (size_t)(mt*16 + li)*32 + g*8);
      }
    }

    // online softmax per nt (row n = nt*16+li; lane holds 16 m-values)
    #pragma unroll
    for (int nt=0; nt<2; nt++){
      f32x4 m01 = vmax4(s[0][nt], s[1][nt]);
      f32x4 m23 = vmax4(s[2][nt], s[3][nt]);
      f32x4 mm4 = vmax4(m01, m23);
      float mx = fmaxf(fmaxf(mm4[0], mm4[1]), fmaxf(mm4[2], mm4[3]));
      mx = fmaxf(mx, __shfl_xor(mx, 16, 64));
      mx = fmaxf(mx, __shfl_xor(mx, 32, 64));
      // defer-max: rescale only when max grew by >8 (log2 domain)
      if (__any(mx > mrun[nt] + 8.0f)){
        float mnew = fmaxf(mrun[nt], mx);
        float corr = __builtin_exp2f(mrun[nt] - mnew);
        mrun[nt] = mnew;
        srun[nt] *= corr;
        #pragma unroll
        for (int dt=0;dt<2;dt++)
          #pragma unroll
          for (int r=0;r<4;r++) oacc[dt][nt][r] *= corr;
      }
      f32x4 sum4 = {0.f,0.f,0.f,0.f};
      #pragma unroll
      for (int mt=0; mt<4; mt++){
        f32x4 p;
        #pragma unroll
        for (int r=0;r<4;r++) p[r] = __builtin_exp2f(s[mt][nt][r] - mrun[nt]);
        sum4 += p;
        uint32_t pk01, pk23;
        asm("v_cvt_pk_bf16_f32 %0, %1, %2" : "=v"(pk01) : "v"(p[0]), "v"(p[1]));
        asm("v_cvt_pk_bf16_f32 %0, %1, %2" : "=v"(pk23) : "v"(p[2]), "v"(p[3]));
        uint2 u; u.x = pk01; u.y = pk23;
        *(uint2*)&pt[wid][nt*16+li][mt*16 + g*4] = u;
      }
      float sm = sum4[0]+sum4[1]+sum4[2]+sum4[3];
      sm += __shfl_xor(sm, 16, 64);
      sm += __shfl_xor(sm, 32, 64);
      srun[nt] += sm;
    }

    // O^T += V * P^T (per-wave private LDS roundtrip, no barrier)
    #pragma unroll
    for (int ks=0; ks<2; ks++){
      bf16x8 pf[2];
      #pragma unroll
      for (int nt=0; nt<2; nt++)
        pf[nt] = *(const bf16x8*)&pt[wid][nt*16+li][ks*32 + g*8];
      #pragma unroll
      for (int dt=0; dt<2; dt++)
        #pragma unroll
        for (int nt=0; nt<2; nt++)
          oacc[dt][nt] = mfma16(vf[dt][ks], pf[nt], oacc[dt][nt]);
    }
  }

  // epilogue: write unnormalized partials
  const size_t pr = (size_t)(prob*2 + mh);
  #pragma unroll
  for (int nt=0;nt<2;nt++){
    int nn = nw + nt*16 + li;   // 0..1023
    #pragma unroll
    for (int dt=0;dt<2;dt++){
      #pragma unroll
      for (int r=0;r<4;r++)
        po[(pr*32 + dt*16 + g*4 + r)*1024 + nn] = f2bf(oacc[dt][nt][r]);
    }
    if (g == 0){
      pm[pr*1024 + nn] = mrun[nt];
      ps[pr*1024 + nn] = srun[nt];
    }
  }
}

// ---------------- combine the two key-halves (exact flash merge) ----------------
__global__ __launch_bounds__(256)
void combine_halves(const uint16_t* __restrict__ po, const float* __restrict__ pm,
                    const float* __restrict__ ps, float* __restrict__ obuf)
{
  const int v = blockIdx.x*256 + threadIdx.x;   // 0..524287
  const int n4 = v & 255;
  const int d  = (v >> 8) & 31;
  const int prob = v >> 13;                      // 0..63
  const int ba = prob >> 3, h = prob & 7, b = ba >> 2, area = ba & 3;

  const size_t r0 = (size_t)(prob*2    )*1024 + n4*4;
  const size_t r1 = (size_t)(prob*2 + 1)*1024 + n4*4;
  const uint16_t* p0 = po + ((size_t)(prob*2    )*32 + d)*1024 + n4*4;
  const uint16_t* p1 = po + ((size_t)(prob*2 + 1)*32 + d)*1024 + n4*4;

  f32x4 m0 = *(const f32x4*)(pm + r0);
  f32x4 m1 = *(const f32x4*)(pm + r1);
  f32x4 s0 = *(const f32x4*)(ps + r0);
  f32x4 s1 = *(const f32x4*)(ps + r1);

  f32x4 o;
  #pragma unroll
  for (int c=0;c<4;c++){
    float mm = fmaxf(m0[c], m1[c]);
    float u0 = __builtin_exp2f(m0[c] - mm);
    float u1 = __builtin_exp2f(m1[c] - mm);
    float den = s0[c]*u0 + s1[c]*u1;
    o[c] = (bf2f(p0[c])*u0 + bf2f(p1[c])*u1) / den;
  }
  *(f32x4*)(obuf + ((size_t)b*256 + h*32 + d)*4096 + area*1024 + n4*4) = o;
}

// ---------------- depthwise 7x7 conv + BN, accumulate into obuf ----------------
__global__ __launch_bounds__(256)
void dwconv_bn_add(const uint16_t* __restrict__ vhp, const uint16_t* __restrict__ vlp,
                   const float* __restrict__ wpe,
                   const float* __restrict__ gg, const float* __restrict__ bb,
                   const float* __restrict__ bm, const float* __restrict__ bv,
                   float* __restrict__ obuf)
{
  const int t = threadIdx.x;
  const int c = blockIdx.x;
  const int b = blockIdx.y;
  const size_t srow = ((size_t)(b*8 + (c>>5))*32 + (c&31))*4096;
  const uint16_t* sh_ = vhp + srow;
  const uint16_t* sl_ = vlp + srow;
  __shared__ float tile[70*70];
  for (int idx = t; idx < 4900; idx += 256){
    int y = idx/70 - 3, x = idx%70 - 3;
    float v = 0.f;
    if ((unsigned)y < 64u && (unsigned)x < 64u){
      int o = y*64 + x;
      v = bf2f(sh_[o]) + bf2f(sl_[o]);
    }
    tile[idx] = v;
  }
  float wreg[49];
  #pragma unroll
  for (int i=0;i<49;i++) wreg[i] = wpe[c*49 + i];
  float sc = gg[c]*rsqrtf(bv[c]+EPSV);
  float sb = bb[c] - bm[c]*sc;
  __syncthreads();
  float* dst = obuf + ((size_t)b*256 + c)*4096;
  #pragma unroll
  for (int p=0;p<16;p++){
    int pix = t + p*256;
    int y = pix >> 6, x = pix & 63;
    float acc = 0.f;
    #pragma unroll
    for (int ky=0;ky<7;ky++)
      #pragma unroll
      for (int kx=0;kx<7;kx++)
        acc += tile[(y+ky)*70 + x + kx] * wreg[ky*7+kx];
    dst[pix] += acc*sc + sb;
  }
}

extern "C" void kernel_launch(void* const* d_in, const int* in_sizes, int n_in,
                              void* d_out, int out_size, void* d_ws, size_t ws_size,
                              hipStream_t stream) {
  const float* x       = (const float*)d_in[0];
  const float* w_qkv   = (const float*)d_in[1];
  const float* g_qkv   = (const float*)d_in[2];
  const float* b_qkv   = (const float*)d_in[3];
  const float* m_qkv   = (const float*)d_in[4];
  const float* var_qkv = (const float*)d_in[5];
  const float* w_pe    = (const float*)d_in[6];
  const float* g_pe    = (const float*)d_in[7];
  const float* b_pe    = (const float*)d_in[8];
  const float* m_pe    = (const float*)d_in[9];
  const float* var_pe  = (const float*)d_in[10];
  const float* w_proj  = (const float*)d_in[11];
  const float* g_proj  = (const float*)d_in[12];
  const float* b_proj  = (const float*)d_in[13];
  const float* m_proj  = (const float*)d_in[14];
  const float* var_proj= (const float*)d_in[15];

  char* wsb = (char*)d_ws;
  // lifetimes: qk32 (0..16M) dead after repack -> po/pm/ps reuse it.
  //            qth/qtl (24..32M) dead after attn -> obuf reuses them.
  float*     qk32 = (float*)wsb;                          // 16 MiB [bh][64][4096]
  uint16_t*  po   = (uint16_t*)wsb;                       // 8 MiB  [prob2][32][1024] bf16
  float*     pm   = (float*)(wsb + 8388608);              // 512 KiB
  float*     ps   = (float*)(wsb + 8912896);              // 512 KiB
  uint16_t*  vhp  = (uint16_t*)(wsb + 16777216);          // 4 MiB
  uint16_t*  vlp  = (uint16_t*)(wsb + 20971520);          // 4 MiB
  uint16_t*  qth  = (uint16_t*)(wsb + 25165824);          // 4 MiB
  uint16_t*  qtl  = (uint16_t*)(wsb + 29360128);          // 4 MiB
  uint16_t*  kth  = (uint16_t*)(wsb + 33554432);          // 4 MiB
  uint16_t*  ktl  = (uint16_t*)(wsb + 37748736);          // 4 MiB (total 40 MiB)
  float*     obuf = (float*)(wsb + 25165824);             // 8 MiB over qth/qtl
  float*     out  = (float*)d_out;

  gemm_bn_kernel<<<dim3(32,6,2), 256, 0, stream>>>(w_qkv, x, nullptr, qk32, vhp, vlp,
      g_qkv, b_qkv, m_qkv, var_qkv, 768, 1);
  repack_qk<<<dim3(32,2,16), 256, 0, stream>>>(qk32, qth, qtl, kth, ktl);
  attn_kernel<<<dim3(1024), 256, 0, stream>>>(qth, qtl, kth, ktl, vhp, po, pm, ps);
  combine_halves<<<dim3(2048), 256, 0, stream>>>(po, pm, ps, obuf);
  dwconv_bn_add<<<dim3(256,2), 256, 0, stream>>>(vhp, vlp, w_pe,
      g_pe, b_pe, m_pe, var_pe, obuf);
  gemm_bn_kernel<<<dim3(32,2,2), 256, 0, stream>>>(w_proj, obuf, out, nullptr, nullptr, nullptr,
      g_proj, b_proj, m_proj, var_proj, 256, 0);
}

// Round 6
// 135.018 us; speedup vs baseline: 1.6216x; 1.0801x over previous
//
#include <hip/hip_runtime.h>
#include <stdint.h>

#define EPSV 1e-5f

typedef __attribute__((ext_vector_type(4))) float f32x4;
typedef __attribute__((ext_vector_type(8))) short bf16x8;

__device__ __forceinline__ unsigned short f2bf(float x){
  union{float f; uint32_t u;} a; a.f=x;
  uint32_t r = a.u + 0x7fffu + ((a.u>>16)&1u);
  return (unsigned short)(r>>16);
}
__device__ __forceinline__ float bf2f(unsigned short u){
  union{uint32_t x; float f;} a; a.x = (uint32_t)u<<16; return a.f;
}
// split float into bf16 hi (truncated) + bf16 lo (RNE of remainder)
__device__ __forceinline__ void split2(float x, unsigned short& h, unsigned short& l){
  union{float f; uint32_t u;} a; a.f=x;
  union{uint32_t u; float f;} b; b.u = a.u & 0xffff0000u;
  h = (unsigned short)(b.u>>16);
  l = f2bf(x - b.f);
}
__device__ __forceinline__ f32x4 mfma16(bf16x8 a, bf16x8 b, f32x4 c){
  return __builtin_amdgcn_mfma_f32_16x16x32_bf16(a, b, c, 0, 0, 0);
}
__device__ __forceinline__ f32x4 vmax4(f32x4 a, f32x4 b){
  f32x4 r; r[0]=fmaxf(a[0],b[0]); r[1]=fmaxf(a[1],b[1]);
  r[2]=fmaxf(a[2],b[2]); r[3]=fmaxf(a[3],b[3]); return r;
}

#define QF 0.25503464f   /* 1/sqrt(32) * log2(e) */

// ---------------- prep: fold BN scale into W, split hi/lo, emit shift ----------------
__global__ __launch_bounds__(256)
void split_w(const float* __restrict__ W,
             const float* __restrict__ gg, const float* __restrict__ bb,
             const float* __restrict__ bm, const float* __restrict__ bv,
             uint16_t* __restrict__ wh, uint16_t* __restrict__ wl,
             float* __restrict__ shift, int M, int mode)
{
  int i = blockIdx.x*256 + threadIdx.x;      // one per 4 elems
  if (i >= M*64) return;
  int row = i >> 6, c4 = (i & 63)*4;
  float s = gg[row]*rsqrtf(bv[row] + EPSV);
  float sh = bb[row] - bm[row]*s;
  if (mode == 1 && (row % 96) < 32){ s *= QF; sh *= QF; }
  f32x4 v = *(const f32x4*)(W + (size_t)row*256 + c4);
  uint16_t h4[4], l4[4];
  #pragma unroll
  for (int k=0;k<4;k++) split2(v[k]*s, h4[k], l4[k]);
  size_t o = (size_t)row*256 + c4;
  *(uint2*)(wh+o) = *(const uint2*)h4;
  *(uint2*)(wl+o) = *(const uint2*)l4;
  if (c4 == 0) shift[row] = sh;
}

// ---------------- prep: transpose + split [B][256][4096] f32 -> [B][4096][256] hi/lo u16 ----------------
__global__ __launch_bounds__(256)
void split_t(const float* __restrict__ src, uint16_t* __restrict__ dh, uint16_t* __restrict__ dl)
{
  __shared__ float tile[32][33];
  const int t = threadIdx.x;
  const int n0 = blockIdx.x*32, c0 = blockIdx.y*32, b = blockIdx.z;
  const float* s = src + ((size_t)b*256 + c0)*4096 + n0;
  #pragma unroll
  for (int i=0;i<4;i++){
    int idx = t + i*256; int cl = idx>>5, nl = idx&31;
    tile[cl][nl] = s[(size_t)cl*4096 + nl];
  }
  __syncthreads();
  int nl = t>>3, cg = (t&7)*4;
  uint16_t h4[4], l4[4];
  #pragma unroll
  for (int k=0;k<4;k++) split2(tile[cg+k][nl], h4[k], l4[k]);
  size_t o = ((size_t)b*4096 + n0+nl)*256 + c0 + cg;
  *(uint2*)(dh+o) = *(const uint2*)h4;
  *(uint2*)(dl+o) = *(const uint2*)l4;
}

// ---------------- LDS-free GEMM: Out[b][o][n] = sum_c Wsc[o][c]*X[b][n][c] + shift[o] ----------------
// A planes: [M][256] hi/lo (BN scale folded). B planes: [B][4096][256] hi/lo.
// MODE 0: fp32 Out. MODE 1: q/k -> qt/kt planes [(b*4+area)*8+h][1024 m][32 d]; v -> vhp/vlp [b*8+h][32 d][4096 n].
template<int WR, int WC, int MODE>
__global__ __launch_bounds__(256)
void gemm_direct(const uint16_t* __restrict__ Awh, const uint16_t* __restrict__ Awl,
                 const float* __restrict__ shift,
                 const uint16_t* __restrict__ Bxh, const uint16_t* __restrict__ Bxl,
                 float* __restrict__ Out,
                 uint16_t* __restrict__ qth, uint16_t* __restrict__ qtl,
                 uint16_t* __restrict__ kth, uint16_t* __restrict__ ktl,
                 uint16_t* __restrict__ vhp, uint16_t* __restrict__ vlp,
                 int M)
{
  constexpr int NA = WR/16, NB = WC/16;
  const int t = threadIdx.x, lane = t&63, wid = t>>6;
  const int g = lane>>4, li = lane&15;
  const int m0 = blockIdx.y*(2*WR) + (wid>>1)*WR;
  const int n0 = blockIdx.x*(2*WC) + (wid&1)*WC;
  const int b = blockIdx.z;
  const uint16_t* Bh = Bxh + (size_t)b*4096*256;
  const uint16_t* Bl = Bxl + (size_t)b*4096*256;

  f32x4 acc[NA][NB];
  #pragma unroll
  for (int i=0;i<NA;i++)
    #pragma unroll
    for (int j=0;j<NB;j++){ f32x4 z={0.f,0.f,0.f,0.f}; acc[i][j]=z; }

  bf16x8 ah0[NA], al0[NA], bh0[NB], bl0[NB];
  bf16x8 ah1[NA], al1[NA], bh1[NB], bl1[NB];

#define GLOAD(AH,AL,BH,BL,KS) do{ \
    _Pragma("unroll") for (int i=0;i<NA;i++){ \
      size_t ao = (size_t)(m0+i*16+li)*256 + (KS)*32 + g*8; \
      AH[i] = *(const bf16x8*)(Awh+ao); AL[i] = *(const bf16x8*)(Awl+ao); } \
    _Pragma("unroll") for (int j=0;j<NB;j++){ \
      size_t bo = (size_t)(n0+j*16+li)*256 + (KS)*32 + g*8; \
      BH[j] = *(const bf16x8*)(Bh+bo); BL[j] = *(const bf16x8*)(Bl+bo); } \
  }while(0)
#define GMM(AH,AL,BH,BL) do{ \
    _Pragma("unroll") for (int i=0;i<NA;i++) \
      _Pragma("unroll") for (int j=0;j<NB;j++){ \
        acc[i][j] = mfma16(AH[i], BH[j], acc[i][j]); \
        acc[i][j] = mfma16(AL[i], BH[j], acc[i][j]); \
        acc[i][j] = mfma16(AH[i], BL[j], acc[i][j]); } \
  }while(0)

  GLOAD(ah0,al0,bh0,bl0,0);
  #pragma unroll
  for (int ks=0; ks<8; ks++){
    if (ks & 1){
      if (ks < 7) GLOAD(ah0,al0,bh0,bl0,ks+1);
      GMM(ah1,al1,bh1,bl1);
    } else {
      if (ks < 7) GLOAD(ah1,al1,bh1,bl1,ks+1);
      GMM(ah0,al0,bh0,bl0);
    }
  }
#undef GLOAD
#undef GMM

  if (MODE == 0){
    #pragma unroll
    for (int i=0;i<NA;i++)
      #pragma unroll
      for (int j=0;j<NB;j++){
        int orow0 = m0 + i*16 + g*4;
        int ocol  = n0 + j*16 + li;
        float* op = Out + ((size_t)b*M + orow0)*4096 + ocol;
        #pragma unroll
        for (int r=0;r<4;r++)
          op[(size_t)r*4096] = acc[i][j][r] + shift[orow0 + r];
      }
  } else {
    #pragma unroll
    for (int i=0;i<NA;i++){
      int base = m0 + i*16;            // multiple of 16; q/k/v type uniform over the 16 rows
      int hh = base/96;
      int rem = base - hh*96;          // {0,16,32,48,64,80}
      #pragma unroll
      for (int j=0;j<NB;j++){
        int ocol = n0 + j*16 + li;
        int area = ocol >> 10, mm = ocol & 1023;
        uint16_t h4[4], l4[4];
        #pragma unroll
        for (int r=0;r<4;r++){
          float val = acc[i][j][r] + shift[base + g*4 + r];
          split2(val, h4[r], l4[r]);
        }
        if (rem < 32){          // q -> [prob][mm][d], d = rem+g*4..+3 (contiguous)
          size_t o = (((size_t)(b*4+area)*8 + hh)*1024 + mm)*32 + rem + g*4;
          *(uint2*)(qth+o) = *(const uint2*)h4;
          *(uint2*)(qtl+o) = *(const uint2*)l4;
        } else if (rem < 64){   // k
          size_t o = (((size_t)(b*4+area)*8 + hh)*1024 + mm)*32 + (rem-32) + g*4;
          *(uint2*)(kth+o) = *(const uint2*)h4;
          *(uint2*)(ktl+o) = *(const uint2*)l4;
        } else {                // v -> [b*8+h][d][n]
          size_t vrow = (size_t)(b*8+hh)*32 + (rem-64) + g*4;
          #pragma unroll
          for (int r=0;r<4;r++){
            vhp[(vrow + r)*4096 + ocol] = h4[r];
            vlp[(vrow + r)*4096 + ocol] = l4[r];
          }
        }
      }
    }
  }
}

// ---------------- split-m flash attention: 32 q-rows/wave, half the keys per block ----------------
__global__ __launch_bounds__(256)
void attn_kernel(const uint16_t* __restrict__ qth, const uint16_t* __restrict__ qtl,
                 const uint16_t* __restrict__ kth, const uint16_t* __restrict__ ktl,
                 const uint16_t* __restrict__ vh,
                 uint16_t* __restrict__ po, float* __restrict__ pm, float* __restrict__ ps)
{
  const int t = threadIdx.x, lane = t & 63, wid = t >> 6;
  const int g = lane >> 4, li = lane & 15;
  const int bid  = blockIdx.x;           // 0..1023
  const int xcd  = bid & 7;
  const int rr   = bid >> 3;             // 0..127
  const int prob = xcd*8 + (rr >> 4);    // 0..63 — bijective
  const int sub  = rr & 15;
  const int nblk = sub >> 1;             // 0..7
  const int mh   = sub & 1;              // key half
  const int ba = prob >> 3, h = prob & 7;
  const int b = ba >> 2, area = ba & 3;

  __shared__ __align__(16) unsigned short pt[4][32][72];

  const size_t qkrow = (size_t)prob*1024;
  const int nw = nblk*128 + wid*32;
  const int mbase = mh*512;

  bf16x8 qh[2], ql[2];
  #pragma unroll
  for (int nt=0; nt<2; nt++){
    qh[nt] = *(const bf16x8*)(qth + (qkrow + nw + nt*16 + li)*32 + g*8);
    ql[nt] = *(const bf16x8*)(qtl + (qkrow + nw + nt*16 + li)*32 + g*8);
  }

  const uint16_t* kbh = kth + (qkrow + mbase)*32;
  const uint16_t* kbl = ktl + (qkrow + mbase)*32;
  const uint16_t* vb  = vh + ((size_t)(b*8+h)*32)*4096 + area*1024 + mbase;

  float mrun[2] = {-1e30f, -1e30f};
  float srun[2] = {0.f, 0.f};
  f32x4 oacc[2][2];
  #pragma unroll
  for (int dt=0;dt<2;dt++)
    #pragma unroll
    for (int nt=0;nt<2;nt++){ f32x4 z = {0.f,0.f,0.f,0.f}; oacc[dt][nt] = z; }

  bf16x8 kh[4], kl[4];
  #pragma unroll
  for (int mt=0;mt<4;mt++){
    kh[mt] = *(const bf16x8*)(kbh + (size_t)(mt*16 + li)*32 + g*8);
    kl[mt] = *(const bf16x8*)(kbl + (size_t)(mt*16 + li)*32 + g*8);
  }

  for (int m0 = 0; m0 < 512; m0 += 64){
    bf16x8 vf[2][2];
    #pragma unroll
    for (int dt=0;dt<2;dt++)
      #pragma unroll
      for (int ks=0;ks<2;ks++)
        vf[dt][ks] = *(const bf16x8*)(vb + (size_t)(dt*16+li)*4096 + m0 + ks*32 + g*8);

    f32x4 s[4][2];
    #pragma unroll
    for (int mt=0;mt<4;mt++)
      #pragma unroll
      for (int nt=0;nt<2;nt++){
        f32x4 z = {0.f,0.f,0.f,0.f};
        z = mfma16(kh[mt], qh[nt], z);
        z = mfma16(kl[mt], qh[nt], z);
        z = mfma16(kh[mt], ql[nt], z);
        s[mt][nt] = z;
      }

    if (m0 < 448){
      const uint16_t* nbh = kbh + (size_t)(m0+64)*32;
      const uint16_t* nbl = kbl + (size_t)(m0+64)*32;
      #pragma unroll
      for (int mt=0;mt<4;mt++){
        kh[mt] = *(const bf16x8*)(nbh + (size_t)(mt*16 + li)*32 + g*8);
        kl[mt] = *(const bf16x8*)(nbl + (size_t)(mt*16 + li)*32 + g*8);
      }
    }

    #pragma unroll
    for (int nt=0; nt<2; nt++){
      f32x4 m01 = vmax4(s[0][nt], s[1][nt]);
      f32x4 m23 = vmax4(s[2][nt], s[3][nt]);
      f32x4 mm4 = vmax4(m01, m23);
      float mx = fmaxf(fmaxf(mm4[0], mm4[1]), fmaxf(mm4[2], mm4[3]));
      mx = fmaxf(mx, __shfl_xor(mx, 16, 64));
      mx = fmaxf(mx, __shfl_xor(mx, 32, 64));
      if (__any(mx > mrun[nt] + 8.0f)){
        float mnew = fmaxf(mrun[nt], mx);
        float corr = __builtin_exp2f(mrun[nt] - mnew);
        mrun[nt] = mnew;
        srun[nt] *= corr;
        #pragma unroll
        for (int dt=0;dt<2;dt++)
          #pragma unroll
          for (int r=0;r<4;r++) oacc[dt][nt][r] *= corr;
      }
      f32x4 sum4 = {0.f,0.f,0.f,0.f};
      #pragma unroll
      for (int mt=0; mt<4; mt++){
        f32x4 p;
        #pragma unroll
        for (int r=0;r<4;r++) p[r] = __builtin_exp2f(s[mt][nt][r] - mrun[nt]);
        sum4 += p;
        uint32_t pk01, pk23;
        asm("v_cvt_pk_bf16_f32 %0, %1, %2" : "=v"(pk01) : "v"(p[0]), "v"(p[1]));
        asm("v_cvt_pk_bf16_f32 %0, %1, %2" : "=v"(pk23) : "v"(p[2]), "v"(p[3]));
        uint2 u; u.x = pk01; u.y = pk23;
        *(uint2*)&pt[wid][nt*16+li][mt*16 + g*4] = u;
      }
      float sm = sum4[0]+sum4[1]+sum4[2]+sum4[3];
      sm += __shfl_xor(sm, 16, 64);
      sm += __shfl_xor(sm, 32, 64);
      srun[nt] += sm;
    }

    #pragma unroll
    for (int ks=0; ks<2; ks++){
      bf16x8 pf[2];
      #pragma unroll
      for (int nt=0; nt<2; nt++)
        pf[nt] = *(const bf16x8*)&pt[wid][nt*16+li][ks*32 + g*8];
      #pragma unroll
      for (int dt=0; dt<2; dt++)
        #pragma unroll
        for (int nt=0; nt<2; nt++)
          oacc[dt][nt] = mfma16(vf[dt][ks], pf[nt], oacc[dt][nt]);
    }
  }

  const size_t pr = (size_t)(prob*2 + mh);
  #pragma unroll
  for (int nt=0;nt<2;nt++){
    int nn = nw + nt*16 + li;
    #pragma unroll
    for (int dt=0;dt<2;dt++){
      #pragma unroll
      for (int r=0;r<4;r++)
        po[(pr*32 + dt*16 + g*4 + r)*1024 + nn] = f2bf(oacc[dt][nt][r]);
    }
    if (g == 0){
      pm[pr*1024 + nn] = mrun[nt];
      ps[pr*1024 + nn] = srun[nt];
    }
  }
}

// ---------------- combine the two key-halves (exact flash merge) ----------------
__global__ __launch_bounds__(256)
void combine_halves(const uint16_t* __restrict__ po, const float* __restrict__ pm,
                    const float* __restrict__ ps, float* __restrict__ obuf)
{
  const int v = blockIdx.x*256 + threadIdx.x;
  const int n4 = v & 255;
  const int d  = (v >> 8) & 31;
  const int prob = v >> 13;
  const int ba = prob >> 3, h = prob & 7, b = ba >> 2, area = ba & 3;

  const size_t r0 = (size_t)(prob*2    )*1024 + n4*4;
  const size_t r1 = (size_t)(prob*2 + 1)*1024 + n4*4;
  const uint16_t* p0 = po + ((size_t)(prob*2    )*32 + d)*1024 + n4*4;
  const uint16_t* p1 = po + ((size_t)(prob*2 + 1)*32 + d)*1024 + n4*4;

  f32x4 m0 = *(const f32x4*)(pm + r0);
  f32x4 m1 = *(const f32x4*)(pm + r1);
  f32x4 s0 = *(const f32x4*)(ps + r0);
  f32x4 s1 = *(const f32x4*)(ps + r1);

  f32x4 o;
  #pragma unroll
  for (int c=0;c<4;c++){
    float mm = fmaxf(m0[c], m1[c]);
    float u0 = __builtin_exp2f(m0[c] - mm);
    float u1 = __builtin_exp2f(m1[c] - mm);
    float den = s0[c]*u0 + s1[c]*u1;
    o[c] = (bf2f(p0[c])*u0 + bf2f(p1[c])*u1) / den;
  }
  *(f32x4*)(obuf + ((size_t)b*256 + h*32 + d)*4096 + area*1024 + n4*4) = o;
}

// ---------------- depthwise 7x7 conv + BN, accumulate into obuf ----------------
__global__ __launch_bounds__(256)
void dwconv_bn_add(const uint16_t* __restrict__ vhp, const uint16_t* __restrict__ vlp,
                   const float* __restrict__ wpe,
                   const float* __restrict__ gg, const float* __restrict__ bb,
                   const float* __restrict__ bm, const float* __restrict__ bv,
                   float* __restrict__ obuf)
{
  const int t = threadIdx.x;
  const int c = blockIdx.x;
  const int b = blockIdx.y;
  const size_t srow = ((size_t)(b*8 + (c>>5))*32 + (c&31))*4096;
  const uint16_t* sh_ = vhp + srow;
  const uint16_t* sl_ = vlp + srow;
  __shared__ float tile[70*70];
  for (int idx = t; idx < 4900; idx += 256){
    int y = idx/70 - 3, x = idx%70 - 3;
    float v = 0.f;
    if ((unsigned)y < 64u && (unsigned)x < 64u){
      int o = y*64 + x;
      v = bf2f(sh_[o]) + bf2f(sl_[o]);
    }
    tile[idx] = v;
  }
  float wreg[49];
  #pragma unroll
  for (int i=0;i<49;i++) wreg[i] = wpe[c*49 + i];
  float sc = gg[c]*rsqrtf(bv[c]+EPSV);
  float sb = bb[c] - bm[c]*sc;
  __syncthreads();
  float* dst = obuf + ((size_t)b*256 + c)*4096;
  #pragma unroll
  for (int p=0;p<16;p++){
    int pix = t + p*256;
    int y = pix >> 6, x = pix & 63;
    float acc = 0.f;
    #pragma unroll
    for (int ky=0;ky<7;ky++)
      #pragma unroll
      for (int kx=0;kx<7;kx++)
        acc += tile[(y+ky)*70 + x + kx] * wreg[ky*7+kx];
    dst[pix] += acc*sc + sb;
  }
}

extern "C" void kernel_launch(void* const* d_in, const int* in_sizes, int n_in,
                              void* d_out, int out_size, void* d_ws, size_t ws_size,
                              hipStream_t stream) {
  const float* x       = (const float*)d_in[0];
  const float* w_qkv   = (const float*)d_in[1];
  const float* g_qkv   = (const float*)d_in[2];
  const float* b_qkv   = (const float*)d_in[3];
  const float* m_qkv   = (const float*)d_in[4];
  const float* var_qkv = (const float*)d_in[5];
  const float* w_pe    = (const float*)d_in[6];
  const float* g_pe    = (const float*)d_in[7];
  const float* b_pe    = (const float*)d_in[8];
  const float* m_pe    = (const float*)d_in[9];
  const float* var_pe  = (const float*)d_in[10];
  const float* w_proj  = (const float*)d_in[11];
  const float* g_proj  = (const float*)d_in[12];
  const float* b_proj  = (const float*)d_in[13];
  const float* m_proj  = (const float*)d_in[14];
  const float* var_proj= (const float*)d_in[15];

  char* wsb = (char*)d_ws;
  // time-disjoint aliasing, peak ~34.3 MiB (ws proven >= 40 MiB):
  uint16_t* qth  = (uint16_t*)(wsb + 0x0000000);   // 4 MiB (steps 3-4)
  uint16_t* qtl  = (uint16_t*)(wsb + 0x0400000);   // 4 MiB
  uint16_t* kth  = (uint16_t*)(wsb + 0x0800000);   // 4 MiB (steps 3-4)
  uint16_t* ktl  = (uint16_t*)(wsb + 0x0C00000);   // 4 MiB
  float*    obuf = (float*)   (wsb + 0x0000000);   // 8 MiB (steps 5-7, over qth/qtl — dead)
  uint16_t* vhp  = (uint16_t*)(wsb + 0x1000000);   // 4 MiB (steps 3-6)
  uint16_t* vlp  = (uint16_t*)(wsb + 0x1400000);   // 4 MiB
  uint16_t* Xth  = (uint16_t*)(wsb + 0x1800000);   // 4 MiB (steps 1-3)
  uint16_t* Xtl  = (uint16_t*)(wsb + 0x1C00000);   // 4 MiB
  uint16_t* po   = (uint16_t*)(wsb + 0x1800000);   // 8 MiB (steps 4-5, over Xth/Xtl — dead)
  uint16_t* Oth  = (uint16_t*)(wsb + 0x1800000);   // 4 MiB (steps 7-8, over po — dead)
  uint16_t* Otl  = (uint16_t*)(wsb + 0x1C00000);   // 4 MiB
  float*    pm   = (float*)   (wsb + 0x2000000);   // 512 KiB (steps 4-5)
  float*    ps   = (float*)   (wsb + 0x2080000);   // 512 KiB
  uint16_t* Wqh  = (uint16_t*)(wsb + 0x2100000);   // 384 KiB (steps 2-3)
  uint16_t* Wql  = (uint16_t*)(wsb + 0x2160000);   // 384 KiB
  float*    shq  = (float*)   (wsb + 0x21C0000);   // 3 KiB
  uint16_t* Wph  = (uint16_t*)(wsb + 0x2200000);   // 128 KiB (steps 2-8)
  uint16_t* Wpl  = (uint16_t*)(wsb + 0x2220000);   // 128 KiB
  float*    shp  = (float*)   (wsb + 0x2240000);   // 1 KiB
  float*    out  = (float*)d_out;

  // 1. transpose+split x
  split_t<<<dim3(128,8,2), 256, 0, stream>>>(x, Xth, Xtl);
  // 2. weight prep
  split_w<<<dim3(192), 256, 0, stream>>>(w_qkv, g_qkv, b_qkv, m_qkv, var_qkv, Wqh, Wql, shq, 768, 1);
  split_w<<<dim3(64),  256, 0, stream>>>(w_proj, g_proj, b_proj, m_proj, var_proj, Wph, Wpl, shp, 256, 0);
  // 3. qkv GEMM (LDS-free), q/k written directly in attention layout
  gemm_direct<32,64,1><<<dim3(32,12,2), 256, 0, stream>>>(Wqh, Wql, shq, Xth, Xtl,
      nullptr, qth, qtl, kth, ktl, vhp, vlp, 768);
  // 4. attention (split-m)
  attn_kernel<<<dim3(1024), 256, 0, stream>>>(qth, qtl, kth, ktl, vhp, po, pm, ps);
  // 5. merge halves
  combine_halves<<<dim3(2048), 256, 0, stream>>>(po, pm, ps, obuf);
  // 6. dwconv + BN add
  dwconv_bn_add<<<dim3(256,2), 256, 0, stream>>>(vhp, vlp, w_pe, g_pe, b_pe, m_pe, var_pe, obuf);
  // 7. transpose+split obuf for proj
  split_t<<<dim3(128,8,2), 256, 0, stream>>>(obuf, Oth, Otl);
  // 8. proj GEMM (LDS-free)
  gemm_direct<32,32,0><<<dim3(64,4,2), 256, 0, stream>>>(Wph, Wpl, shp, Oth, Otl,
      out, nullptr, nullptr, nullptr, nullptr, nullptr, nullptr, 256);
}